// Round 10
// baseline (70.118 us; speedup 1.0000x reference)
//
#include <hip/hip_runtime.h>

// HungarianMatcher batched cost matrix. B=64, Q=900, T=300, C=80.
// cost = 5*cbbox + (2*ccls + 2) - 2*(inter*ca + uni^2)/(uni*ca)
//
// R10: fixed-assignment 2D thread mapping, fully static main loop.
// Thread (tq=tid/75, tt=tid%75) owns t-group tt (4 t's; 8 fields -> 32
// VGPRs, loaded ONCE) x 5 q's (q = q0 + tq + 4j, j=0..4). Main loop is
// #pragma unroll 5: per q only 2 broadcast b128 + 4 imm-offset cls
// gathers + ~33 VALU + 1 float4 store; iterations independent -> loads
// hoist across the flat body (the ILP every 1.5-iter variant lacked).
// VALU trims: min+max identity cw=(pw+tw)-wi_raw, fmaf(num*r,-2,c),
// derived areas. launch_bounds(320,8) pins VGPR<=64 (8 waves/SIMD).

constexpr int B = 64, Q = 900, T = 300, C = 80;
constexpr int QTILE = 20;            // 45 q-tiles -> grid 2880
constexpr int BLOCK = 320;           // 300 active (4x75), 5 waves
constexpr int NQ    = QTILE / 4;     // 5 q per thread
constexpr float ALPHA = 0.25f;
constexpr float EPSF  = 1e-8f;

__device__ __forceinline__ float fast_rcp(float x) {
    return __builtin_amdgcn_rcpf(x);
}

__device__ __forceinline__ float focal2(float x) {
    float pr = fast_rcp(1.0f + __expf(-x));
    float om = 1.0f - pr;
    float pos = ALPHA * om * om * (-__logf(pr + EPSF));
    float neg = (1.0f - ALPHA) * pr * pr * (-__logf(om + EPSF));
    return 2.0f * (pos - neg) + 2.0f;    // pre-scaled: W_CLASS*cls + 2
}

__global__ __launch_bounds__(BLOCK, 8) void matcher_cost_kernel(
    const float* __restrict__ logits,    // [B,Q,C]
    const float* __restrict__ pboxes,    // [B,Q,4] cxcywh
    const int*   __restrict__ tlabels,   // [B,T]
    const float* __restrict__ tboxes,    // [B,T,4] cxcywh
    float* __restrict__ out)             // [B,Q,T]
{
    __shared__ float4 s_t[8][T / 4];     // cx,cy,w,h,x0,y0,x1,y1 (9.6 KB)
    __shared__ int4   s_tl[T / 4];
    __shared__ float  s_cls[QTILE * C];  // 6.4 KB
    __shared__ float4 s_pA[QTILE];       // cx,cy,w,h
    __shared__ float4 s_pB[QTILE];       // x0,y0,x1,y1

    const int bid = blockIdx.x;
    const int b   = bid / (Q / QTILE);
    const int q0  = (bid % (Q / QTILE)) * QTILE;
    const int tid = threadIdx.x;

    // ---- stage target fields (one guarded pass, 300 active) ----
    if (tid < T) {
        float4 bx = *(const float4*)(tboxes + ((size_t)b * T + tid) * 4);
        float x0 = bx.x - 0.5f * bx.z, y0 = bx.y - 0.5f * bx.w;
        float x1 = bx.x + 0.5f * bx.z, y1 = bx.y + 0.5f * bx.w;
        ((float*)&s_t[0][0])[tid] = bx.x;
        ((float*)&s_t[1][0])[tid] = bx.y;
        ((float*)&s_t[2][0])[tid] = bx.z;
        ((float*)&s_t[3][0])[tid] = bx.w;
        ((float*)&s_t[4][0])[tid] = x0;
        ((float*)&s_t[5][0])[tid] = y0;
        ((float*)&s_t[6][0])[tid] = x1;
        ((float*)&s_t[7][0])[tid] = y1;
        ((int*)&s_tl[0])[tid]     = tlabels[(size_t)b * T + tid];
    }
    if (tid < QTILE) {
        float4 bx = *(const float4*)(pboxes + ((size_t)b * Q + q0 + tid) * 4);
        s_pA[tid] = bx;
        s_pB[tid] = make_float4(bx.x - 0.5f * bx.z, bx.y - 0.5f * bx.w,
                                bx.x + 0.5f * bx.z, bx.y + 0.5f * bx.w);
    }
    // ---- focal class table: 1600 entries, exactly 5 per thread ----
    {
        const float* lg = logits + ((size_t)b * Q + q0) * C;
        #pragma unroll
        for (int s = 0; s < QTILE * C / BLOCK; ++s)
            s_cls[s * BLOCK + tid] = focal2(lg[s * BLOCK + tid]);
    }

    __syncthreads();

    if (tid >= T) return;

    const int tq = tid / 75;             // 0..3
    const int tt = tid - tq * 75;        // 0..74 (t-group)

    // ---- t-group fields -> registers, loaded ONCE (8 x b128) ----
    float4 Tcx = s_t[0][tt], Tcy = s_t[1][tt];
    float4 Tw  = s_t[2][tt], Th  = s_t[3][tt];
    float4 Tx0 = s_t[4][tt], Ty0 = s_t[5][tt];
    float4 Tx1 = s_t[6][tt], Ty1 = s_t[7][tt];
    int4   lab = s_tl[tt];

    const float* cls0 = s_cls + tq * C;  // + j*4*C as imm offsets
    float* op = out + ((size_t)b * Q + q0 + tq) * T + tt * 4;

    #pragma unroll
    for (int j = 0; j < NQ; ++j) {
        const int ql = tq + 4 * j;
        float4 pA = s_pA[ql];            // broadcast b128 (<=2 addrs/wave)
        float4 pB = s_pB[ql];
        float  pa = pA.z * pA.w;
        const float* clsj = cls0 + j * 4 * C;

        float cls_k[4] = { clsj[lab.x], clsj[lab.y], clsj[lab.z], clsj[lab.w] };

        float4 res;
        #pragma unroll
        for (int k = 0; k < 4; ++k) {
            float tcx_ = (&Tcx.x)[k], tcy_ = (&Tcy.x)[k];
            float tw_  = (&Tw.x)[k],  th_  = (&Th.x)[k];
            float tx0_ = (&Tx0.x)[k], ty0_ = (&Ty0.x)[k];
            float tx1_ = (&Tx1.x)[k], ty1_ = (&Ty1.x)[k];

            float wi = fminf(pB.z, tx1_) - fmaxf(pB.x, tx0_);  // raw overlap
            float hi = fminf(pB.w, ty1_) - fmaxf(pB.y, ty0_);
            float iw = fmaxf(wi, 0.0f), ih = fmaxf(hi, 0.0f);
            float inter = iw * ih;
            float ta  = tw_ * th_;
            float uni = (pa + ta) - inter;
            float cw  = (pA.z + tw_) - wi;   // max-min identity: enclosure
            float ch  = (pA.w + th_) - hi;
            float ca  = cw * ch;

            float cbbox = (fabsf(pA.x - tcx_) + fabsf(pA.y - tcy_)) +
                          (fabsf(pA.z - tw_ ) + fabsf(pA.w - th_ ));

            float num = fmaf(uni, uni, inter * ca);
            float r   = fast_rcp(uni * ca);
            float c   = fmaf(5.0f, cbbox, cls_k[k]);
            c = fmaf(num * r, -2.0f, c);

            if (c != c) c = 1.0f;            // nan_to_num; clamp provably no-op

            (&res.x)[k] = c;
        }
        *(float4*)(op + (size_t)(4 * j) * T) = res;   // coalesced 16B
    }
}

extern "C" void kernel_launch(void* const* d_in, const int* in_sizes, int n_in,
                              void* d_out, int out_size, void* d_ws, size_t ws_size,
                              hipStream_t stream) {
    const float* logits  = (const float*)d_in[0];  // [B,Q,C]
    const float* pboxes  = (const float*)d_in[1];  // [B,Q,4]
    const int*   tlabels = (const int*)  d_in[2];  // [B,T]
    const float* tboxes  = (const float*)d_in[3];  // [B,T,4]
    float* out = (float*)d_out;                    // [B,Q,T]

    dim3 grid(B * (Q / QTILE));   // 2880 blocks
    dim3 block(BLOCK);
    matcher_cost_kernel<<<grid, block, 0, stream>>>(logits, pboxes, tlabels, tboxes, out);
}

// Round 11
// 32.544 us; speedup vs baseline: 2.1545x; 2.1545x over previous
//
#include <hip/hip_runtime.h>

// HungarianMatcher batched cost matrix. B=64, Q=900, T=300, C=80.
// cost = 5*cbbox + (2*ccls + 2) - 2*(inter*ca + uni^2)/(uni*ca)
//
// R11 = R10 with the register-allocator strangulation removed.
// R10's __launch_bounds__(320,8) forced VGPR=32 < the ~32-reg t-field
// working set alone -> scratch spill (FETCH 95MB, WRITE 218MB, 70-88us).
// Same structure, launch_bounds(320) only: thread (tq,tt) owns t-group
// tt (8 fields in VGPRs, loaded once) x 5 q's, fully unrolled; per q:
// 2 broadcast b128 + 4 imm-offset cls gathers + ~30 VALU + 1 f4 store.

constexpr int B = 64, Q = 900, T = 300, C = 80;
constexpr int QTILE = 20;            // 45 q-tiles -> grid 2880
constexpr int BLOCK = 320;           // 300 active (4x75), 5 waves
constexpr int NQ    = QTILE / 4;     // 5 q per thread
constexpr float ALPHA = 0.25f;
constexpr float EPSF  = 1e-8f;

__device__ __forceinline__ float fast_rcp(float x) {
    return __builtin_amdgcn_rcpf(x);
}

__device__ __forceinline__ float focal2(float x) {
    float pr = fast_rcp(1.0f + __expf(-x));
    float om = 1.0f - pr;
    float pos = ALPHA * om * om * (-__logf(pr + EPSF));
    float neg = (1.0f - ALPHA) * pr * pr * (-__logf(om + EPSF));
    return 2.0f * (pos - neg) + 2.0f;    // pre-scaled: W_CLASS*cls + 2
}

__global__ __launch_bounds__(BLOCK) void matcher_cost_kernel(
    const float* __restrict__ logits,    // [B,Q,C]
    const float* __restrict__ pboxes,    // [B,Q,4] cxcywh
    const int*   __restrict__ tlabels,   // [B,T]
    const float* __restrict__ tboxes,    // [B,T,4] cxcywh
    float* __restrict__ out)             // [B,Q,T]
{
    __shared__ float4 s_t[8][T / 4];     // cx,cy,w,h,x0,y0,x1,y1 (9.6 KB)
    __shared__ int4   s_tl[T / 4];
    __shared__ float  s_cls[QTILE * C];  // 6.4 KB
    __shared__ float4 s_pA[QTILE];       // cx,cy,w,h
    __shared__ float4 s_pB[QTILE];       // x0,y0,x1,y1

    const int bid = blockIdx.x;
    const int b   = bid / (Q / QTILE);
    const int q0  = (bid % (Q / QTILE)) * QTILE;
    const int tid = threadIdx.x;

    // ---- stage target fields (one guarded pass, 300 active) ----
    if (tid < T) {
        float4 bx = *(const float4*)(tboxes + ((size_t)b * T + tid) * 4);
        float x0 = bx.x - 0.5f * bx.z, y0 = bx.y - 0.5f * bx.w;
        float x1 = bx.x + 0.5f * bx.z, y1 = bx.y + 0.5f * bx.w;
        ((float*)&s_t[0][0])[tid] = bx.x;
        ((float*)&s_t[1][0])[tid] = bx.y;
        ((float*)&s_t[2][0])[tid] = bx.z;
        ((float*)&s_t[3][0])[tid] = bx.w;
        ((float*)&s_t[4][0])[tid] = x0;
        ((float*)&s_t[5][0])[tid] = y0;
        ((float*)&s_t[6][0])[tid] = x1;
        ((float*)&s_t[7][0])[tid] = y1;
        ((int*)&s_tl[0])[tid]     = tlabels[(size_t)b * T + tid];
    }
    if (tid < QTILE) {
        float4 bx = *(const float4*)(pboxes + ((size_t)b * Q + q0 + tid) * 4);
        s_pA[tid] = bx;
        s_pB[tid] = make_float4(bx.x - 0.5f * bx.z, bx.y - 0.5f * bx.w,
                                bx.x + 0.5f * bx.z, bx.y + 0.5f * bx.w);
    }
    // ---- focal class table: 1600 entries, exactly 5 per thread ----
    {
        const float* lg = logits + ((size_t)b * Q + q0) * C;
        #pragma unroll
        for (int s = 0; s < QTILE * C / BLOCK; ++s)
            s_cls[s * BLOCK + tid] = focal2(lg[s * BLOCK + tid]);
    }

    __syncthreads();

    if (tid >= T) return;

    const int tq = tid / 75;             // 0..3
    const int tt = tid - tq * 75;        // 0..74 (t-group)

    // ---- t-group fields -> registers, loaded ONCE (8 x b128) ----
    float4 Tcx = s_t[0][tt], Tcy = s_t[1][tt];
    float4 Tw  = s_t[2][tt], Th  = s_t[3][tt];
    float4 Tx0 = s_t[4][tt], Ty0 = s_t[5][tt];
    float4 Tx1 = s_t[6][tt], Ty1 = s_t[7][tt];
    int4   lab = s_tl[tt];

    const float* cls0 = s_cls + tq * C;  // + j*4*C as imm offsets
    float* op = out + ((size_t)b * Q + q0 + tq) * T + tt * 4;

    #pragma unroll
    for (int j = 0; j < NQ; ++j) {
        const int ql = tq + 4 * j;
        float4 pA = s_pA[ql];            // broadcast b128 (<=2 addrs/wave)
        float4 pB = s_pB[ql];
        float  pa = pA.z * pA.w;
        const float* clsj = cls0 + j * 4 * C;

        float cls_k[4] = { clsj[lab.x], clsj[lab.y], clsj[lab.z], clsj[lab.w] };

        float4 res;
        #pragma unroll
        for (int k = 0; k < 4; ++k) {
            float tcx_ = (&Tcx.x)[k], tcy_ = (&Tcy.x)[k];
            float tw_  = (&Tw.x)[k],  th_  = (&Th.x)[k];
            float tx0_ = (&Tx0.x)[k], ty0_ = (&Ty0.x)[k];
            float tx1_ = (&Tx1.x)[k], ty1_ = (&Ty1.x)[k];

            float wi = fminf(pB.z, tx1_) - fmaxf(pB.x, tx0_);  // raw overlap
            float hi = fminf(pB.w, ty1_) - fmaxf(pB.y, ty0_);
            float iw = fmaxf(wi, 0.0f), ih = fmaxf(hi, 0.0f);
            float inter = iw * ih;
            float ta  = tw_ * th_;
            float uni = (pa + ta) - inter;
            float cw  = (pA.z + tw_) - wi;   // max-min identity: enclosure
            float ch  = (pA.w + th_) - hi;
            float ca  = cw * ch;

            float cbbox = (fabsf(pA.x - tcx_) + fabsf(pA.y - tcy_)) +
                          (fabsf(pA.z - tw_ ) + fabsf(pA.w - th_ ));

            float num = fmaf(uni, uni, inter * ca);
            float r   = fast_rcp(uni * ca);
            float c   = fmaf(5.0f, cbbox, cls_k[k]);
            c = fmaf(num * r, -2.0f, c);

            if (c != c) c = 1.0f;            // nan_to_num; clamp provably no-op

            (&res.x)[k] = c;
        }
        *(float4*)(op + (size_t)(4 * j) * T) = res;   // coalesced 16B
    }
}

extern "C" void kernel_launch(void* const* d_in, const int* in_sizes, int n_in,
                              void* d_out, int out_size, void* d_ws, size_t ws_size,
                              hipStream_t stream) {
    const float* logits  = (const float*)d_in[0];  // [B,Q,C]
    const float* pboxes  = (const float*)d_in[1];  // [B,Q,4]
    const int*   tlabels = (const int*)  d_in[2];  // [B,T]
    const float* tboxes  = (const float*)d_in[3];  // [B,T,4]
    float* out = (float*)d_out;                    // [B,Q,T]

    dim3 grid(B * (Q / QTILE));   // 2880 blocks
    dim3 block(BLOCK);
    matcher_cost_kernel<<<grid, block, 0, stream>>>(logits, pboxes, tlabels, tboxes, out);
}

// Round 12
// 31.021 us; speedup vs baseline: 2.2604x; 1.0491x over previous
//
#include <hip/hip_runtime.h>

// HungarianMatcher batched cost matrix. B=64, Q=900, T=300, C=80.
// cost = 5*cbbox + (2*ccls + 2) - 2*(inter*ca + uni^2)/(uni*ca)
//
// R12 = R11 deepened. (a) t-fields straight from global into registers
// (no LDS staging for targets at all); (b) QTILE 36, NQ=9 independent
// unrolled q-iters per thread (staging amortized 1.8x, deeper ILP);
// (c) one-log focal: -log p = L = log(1+e^-x), -log(1-p) = x + L.
// Per q-iter: 2 broadcast b128 + 4 imm-offset cls gathers + ~30 VALU +
// 1 float4 coalesced store. NO min-waves launch_bounds clause (R10's
// spill lesson: FETCH/WRITE must stay at ~11/67.5 MB).

constexpr int B = 64, Q = 900, T = 300, C = 80;
constexpr int QTILE = 36;            // 25 q-tiles -> grid 1600
constexpr int BLOCK = 320;           // 300 active (4x75), 5 waves
constexpr int NQ    = QTILE / 4;     // 9 q per thread
constexpr float ALPHA = 0.25f;

__device__ __forceinline__ float fast_rcp(float x) {
    return __builtin_amdgcn_rcpf(x);
}

// 2*(pos-neg)+2 with one exp, one rcp, one log.
__device__ __forceinline__ float focal2(float x) {
    float t  = __expf(-x);
    float p  = fast_rcp(1.0f + t);
    float L  = __logf(1.0f + t);      // = -log(p)
    float xL = x + L;                 // = -log(1-p)
    float omp = t * p;                // 1-p
    float pos = ALPHA * omp * omp * L;
    float neg = (1.0f - ALPHA) * p * p * xL;
    return fmaf(2.0f, pos - neg, 2.0f);
}

__global__ __launch_bounds__(BLOCK) void matcher_cost_kernel(
    const float* __restrict__ logits,    // [B,Q,C]
    const float* __restrict__ pboxes,    // [B,Q,4] cxcywh
    const int*   __restrict__ tlabels,   // [B,T]
    const float* __restrict__ tboxes,    // [B,T,4] cxcywh
    float* __restrict__ out)             // [B,Q,T]
{
    __shared__ float  s_cls[QTILE * C];  // 11.52 KB
    __shared__ float4 s_pA[QTILE];       // cx,cy,w,h
    __shared__ float4 s_pB[QTILE];       // x0,y0,x1,y1

    const int bid = blockIdx.x;
    const int b   = bid / (Q / QTILE);
    const int q0  = (bid % (Q / QTILE)) * QTILE;
    const int tid = threadIdx.x;

    // ---- pred boxes for this q-tile ----
    if (tid < QTILE) {
        float4 bx = *(const float4*)(pboxes + ((size_t)b * Q + q0 + tid) * 4);
        s_pA[tid] = bx;
        s_pB[tid] = make_float4(bx.x - 0.5f * bx.z, bx.y - 0.5f * bx.w,
                                bx.x + 0.5f * bx.z, bx.y + 0.5f * bx.w);
    }
    // ---- focal class table: 2880 entries, exactly 9 per thread ----
    {
        const float* lg = logits + ((size_t)b * Q + q0) * C;
        #pragma unroll
        for (int s = 0; s < QTILE * C / BLOCK; ++s)
            s_cls[s * BLOCK + tid] = focal2(lg[s * BLOCK + tid]);
    }

    // ---- t-group fields: straight from global into registers ----
    const int tq = tid / 75;             // 0..3 (garbage for tid>=300, unused)
    const int tt = (tid < T) ? (tid - tq * 75) : 0;

    float4 tb[4];
    int4   lab = make_int4(0, 0, 0, 0);
    if (tid < T) {
        const float4* tbp = (const float4*)(tboxes + ((size_t)b * T + tt * 4) * 4);
        tb[0] = tbp[0]; tb[1] = tbp[1]; tb[2] = tbp[2]; tb[3] = tbp[3];
        lab = *(const int4*)(tlabels + (size_t)b * T + tt * 4);
    }
    // derived per-t fields (registers)
    float Tcx[4], Tcy[4], Tw[4], Th[4], Tx0[4], Ty0[4], Tx1[4], Ty1[4];
    #pragma unroll
    for (int k = 0; k < 4; ++k) {
        Tcx[k] = tb[k].x; Tcy[k] = tb[k].y; Tw[k] = tb[k].z; Th[k] = tb[k].w;
        Tx0[k] = tb[k].x - 0.5f * tb[k].z; Ty0[k] = tb[k].y - 0.5f * tb[k].w;
        Tx1[k] = tb[k].x + 0.5f * tb[k].z; Ty1[k] = tb[k].y + 0.5f * tb[k].w;
    }

    __syncthreads();

    if (tid >= T) return;

    const float* cls0 = s_cls + tq * C;  // + j*4*C as imm offsets
    float* op = out + ((size_t)b * Q + q0 + tq) * T + tt * 4;

    #pragma unroll
    for (int j = 0; j < NQ; ++j) {
        const int ql = tq + 4 * j;
        float4 pA = s_pA[ql];            // broadcast b128 (<=2 addrs/wave)
        float4 pB = s_pB[ql];
        float  pa = pA.z * pA.w;
        const float* clsj = cls0 + j * 4 * C;

        float cls_k[4] = { clsj[lab.x], clsj[lab.y], clsj[lab.z], clsj[lab.w] };

        float4 res;
        #pragma unroll
        for (int k = 0; k < 4; ++k) {
            float wi = fminf(pB.z, Tx1[k]) - fmaxf(pB.x, Tx0[k]);  // raw overlap
            float hi = fminf(pB.w, Ty1[k]) - fmaxf(pB.y, Ty0[k]);
            float iw = fmaxf(wi, 0.0f), ih = fmaxf(hi, 0.0f);
            float inter = iw * ih;
            float ta  = Tw[k] * Th[k];
            float uni = (pa + ta) - inter;
            float cw  = (pA.z + Tw[k]) - wi;   // min+max identity: enclosure
            float ch  = (pA.w + Th[k]) - hi;
            float ca  = cw * ch;

            float cbbox = (fabsf(pA.x - Tcx[k]) + fabsf(pA.y - Tcy[k])) +
                          (fabsf(pA.z - Tw[k] ) + fabsf(pA.w - Th[k] ));

            float num = fmaf(uni, uni, inter * ca);
            float r   = fast_rcp(uni * ca);
            float c   = fmaf(5.0f, cbbox, cls_k[k]);
            c = fmaf(num * r, -2.0f, c);

            if (c != c) c = 1.0f;            // nan_to_num; clamp provably no-op

            (&res.x)[k] = c;
        }
        *(float4*)(op + (size_t)(4 * j) * T) = res;   // coalesced 16B
    }
}

extern "C" void kernel_launch(void* const* d_in, const int* in_sizes, int n_in,
                              void* d_out, int out_size, void* d_ws, size_t ws_size,
                              hipStream_t stream) {
    const float* logits  = (const float*)d_in[0];  // [B,Q,C]
    const float* pboxes  = (const float*)d_in[1];  // [B,Q,4]
    const int*   tlabels = (const int*)  d_in[2];  // [B,T]
    const float* tboxes  = (const float*)d_in[3];  // [B,T,4]
    float* out = (float*)d_out;                    // [B,Q,T]

    dim3 grid(B * (Q / QTILE));   // 1600 blocks
    dim3 block(BLOCK);
    matcher_cost_kernel<<<grid, block, 0, stream>>>(logits, pboxes, tlabels, tboxes, out);
}